// Round 13
// baseline (205.686 us; speedup 1.0000x reference)
//
#include <hip/hip_runtime.h>
#include <hip/hip_bf16.h>

// Problem constants (fixed by the reference): B=16, V=8192, N=2048, H=128, C_OUT=7
#define B_GR   16
#define V_PTS  8192
#define N_RES  2048
#define H_DIM  128
#define C_OUT  7
#define SEGS   16
#define NB     512           // x-buckets
#define CPAD   520           // padded per-graph cellstart stride
#define BW     0.203125f     // bucket width = 104/512 = 13/64 (exact fp)
#define G_VERT 512           // sorted vertices per search group
#define S_CHK  8             // slab chunks per group
#define WFIX   2.5f          // fixed slab half-width (pass 1)
#define RES_D  6.2f          // resolved iff computed d <= 6.2 (< 6.25 - 5e-3 fp bound)
#define NVTOT  (B_GR * V_PTS)

// Ledger: r1 pk-f32 not 2x; r2 issue-bound; r3 atomics free; r4/r5 micro nil
// (banked best: r4 brute = 144.6, 5 nodes). r6-r10: pruning needs brute's
// shape. r11: search OK, fallback 111 µs. r12: wide fallback fixed it, but
// top-5 exposed the harness: ~43 µs fillBufferAligned (256 MiB workspace
// re-poison) every iteration + ~5.5 µs per graph node. r12 had 10 nodes.
// r13: same validated algorithm in 5 nodes, 0 memsets — search stores
// per-chunk partials (unconditional -> poison-safe), finalize+fallback
// merged into one ballot-driven kernel, prep recombined.

__device__ __forceinline__ int bucketof(float x) {
    int bk = (int)floorf((x + 52.0f) * (512.0f / 104.0f));
    return bk < 0 ? 0 : (bk > NB - 1 ? NB - 1 : bk);
}
__device__ __forceinline__ float lo_edge(int k) {      // k*(13/64)-52, exact fp
    return (float)k * BW - 52.0f;
}

// one candidate: bit-exact reference sequence + lexicographic (d, orig idx)
__device__ __forceinline__ void eval_one(const float4 c, int id,
                                         float vx, float vy, float vz, float vsq,
                                         float& best, int& bidx) {
    float dot = __fadd_rn(__fadd_rn(__fmul_rn(vx, c.x), __fmul_rn(vy, c.y)),
                          __fmul_rn(vz, c.z));
    float d = __fadd_rn(fmaf(-2.0f, dot, vsq), c.w);
    bool take = (d < best) || ((d == best) && (id < bidx));
    best = take ? d : best;
    bidx = take ? id : bidx;
}

// monotone-flipped (d, idx) packing — u64 < == lexicographic (d, idx) <
__device__ __forceinline__ unsigned long long packmin(float d, int idx) {
    unsigned int bits = __float_as_uint(d);
    unsigned int key  = bits ^ (unsigned int)(((int)bits >> 31) | 0x80000000);
    return ((unsigned long long)key << 32) | (unsigned int)idx;
}

// ---------------------------------------------------------------------------
// Kernel 0 (prep): per graph — counting-sort RESIDUES by x-bucket into
// (float4 x,y,z,csq + orig idx u32) + exclusive bucket starts; counting-sort
// VERTICES into float4 (x,y,z,vsq); zero the hit mask. All squared norms use
// the exact reference fp sequence. Within-bucket order arbitrary — selection
// is lexicographic. 16 blocks x 256 threads (~18 µs measured r10-accounting;
// cheaper than the r12 3-kernel+2-fill split once node overhead is counted).
// ---------------------------------------------------------------------------
__global__ __launch_bounds__(256) void k_prep(const float* __restrict__ coords,
                                              const float* __restrict__ verts,
                                              float4* __restrict__ sf4g,
                                              unsigned int* __restrict__ sidxg,
                                              unsigned int* __restrict__ cellsg,
                                              float4* __restrict__ vf4g,
                                              float* __restrict__ msk) {
    __shared__ unsigned int hist[NB];
    __shared__ unsigned int sA[NB], sB[NB];
    __shared__ unsigned int cursor[NB];
    const int b = blockIdx.x;
    const int tid = threadIdx.x;

    // ---- residues ----
    for (int i = tid; i < NB; i += 256) hist[i] = 0;
    for (int i = tid; i < N_RES; i += 256) msk[b * N_RES + i] = 0.0f;
    __syncthreads();

    const float* cb = coords + (size_t)b * N_RES * 3;
    for (int i = tid; i < N_RES; i += 256)
        atomicAdd(&hist[bucketof(cb[i * 3])], 1u);
    __syncthreads();

    for (int i = tid; i < NB; i += 256) sA[i] = hist[i];
    __syncthreads();
    unsigned int* src = sA;
    unsigned int* dst = sB;
    for (int off = 1; off < NB; off <<= 1) {            // Hillis-Steele inclusive
        for (int i = tid; i < NB; i += 256)
            dst[i] = src[i] + (i >= off ? src[i - off] : 0u);
        __syncthreads();
        unsigned int* t = src; src = dst; dst = t;
    }
    for (int i = tid; i < NB; i += 256) {
        unsigned int ex = src[i] - hist[i];             // exclusive start
        cellsg[b * CPAD + i] = ex;
        cursor[i] = ex;
    }
    if (tid == 0) cellsg[b * CPAD + NB] = N_RES;
    __syncthreads();

    for (int i = tid; i < N_RES; i += 256) {
        float x = cb[i * 3 + 0];
        float y = cb[i * 3 + 1];
        float z = cb[i * 3 + 2];
        float csq = __fadd_rn(__fadd_rn(__fmul_rn(x, x), __fmul_rn(y, y)), __fmul_rn(z, z));
        unsigned int pos = atomicAdd(&cursor[bucketof(x)], 1u);
        sf4g[(size_t)b * N_RES + pos] = make_float4(x, y, z, csq);
        sidxg[(size_t)b * N_RES + pos] = (unsigned int)i;
    }
    __syncthreads();

    // ---- vertices (reuse hist/scan/cursor) ----
    for (int i = tid; i < NB; i += 256) hist[i] = 0;
    __syncthreads();
    const float* vb = verts + (size_t)b * V_PTS * 3;
    for (int i = tid; i < V_PTS; i += 256)
        atomicAdd(&hist[bucketof(vb[i * 3])], 1u);
    __syncthreads();
    for (int i = tid; i < NB; i += 256) sA[i] = hist[i];
    __syncthreads();
    src = sA; dst = sB;
    for (int off = 1; off < NB; off <<= 1) {
        for (int i = tid; i < NB; i += 256)
            dst[i] = src[i] + (i >= off ? src[i - off] : 0u);
        __syncthreads();
        unsigned int* t = src; src = dst; dst = t;
    }
    for (int i = tid; i < NB; i += 256)
        cursor[i] = src[i] - hist[i];
    __syncthreads();
    for (int i = tid; i < V_PTS; i += 256) {
        float x = vb[i * 3 + 0];
        float y = vb[i * 3 + 1];
        float z = vb[i * 3 + 2];
        float vsq = __fadd_rn(__fadd_rn(__fmul_rn(x, x), __fmul_rn(y, y)), __fmul_rn(z, z));
        unsigned int pos = atomicAdd(&cursor[bucketof(x)], 1u);
        vf4g[(size_t)b * V_PTS + pos] = make_float4(x, y, z, vsq);
    }
}

// ---------------------------------------------------------------------------
// Kernel 1 (search): FROZEN structure from r11/r12. Group of 512 sorted
// vertices, fixed W=2.5 slab split into 8 chunks, VPT=2, broadcast global
// reads. Merge changed: each chunk writes its partial UNCONDITIONALLY to
// part[s][vertex] (plain coalesced u64 store) — no atomics, no init memset,
// workspace-poison-safe. 2048 blocks x 256 thr = 32 waves/CU.
// ---------------------------------------------------------------------------
__global__ __launch_bounds__(256, 8) void k_search(const float4* __restrict__ vf4g,
                                                   const float4* __restrict__ sf4g,
                                                   const unsigned int* __restrict__ sidxg,
                                                   const unsigned int* __restrict__ cellsg,
                                                   unsigned long long* __restrict__ part) {
    const int blk = blockIdx.x;
    const int s   = blk & (S_CHK - 1);
    const int grp = blk >> 3;
    const int b   = grp >> 4;
    const int g0  = grp << 9;

    const int kf = bucketof(vf4g[g0].x);
    const int kl = bucketof(vf4g[g0 + G_VERT - 1].x);
    const int j0 = (int)cellsg[b * CPAD + bucketof(lo_edge(kf) - WFIX)];
    const int j1 = (int)cellsg[b * CPAD + bucketof(lo_edge(kl + 1) + WFIX) + 1];
    const int len = j1 - j0;
    const int jA = j0 + (len * s) / S_CHK;
    const int jB = j0 + (len * (s + 1)) / S_CHK;

    const int t = threadIdx.x;
    const float4 v0 = vf4g[g0 + t];
    const float4 v1 = vf4g[g0 + t + 256];

    float b0 = 3.402823466e+38f, b1 = 3.402823466e+38f;
    int   i0 = 0, i1 = 0;
    const float4* sp = sf4g + (size_t)b * N_RES;
    const unsigned int* ip = sidxg + (size_t)b * N_RES;

#pragma unroll 2
    for (int j = jA; j < jB; ++j) {
        const float4 c = sp[j];                         // broadcast (all lanes same)
        const int id = (int)ip[j];
        eval_one(c, id, v0.x, v0.y, v0.z, v0.w, b0, i0);
        eval_one(c, id, v1.x, v1.y, v1.z, v1.w, b1, i1);
    }

    unsigned long long* op = part + (size_t)s * NVTOT + g0 + t;
    op[0]   = packmin(b0, i0);                          // plain coalesced stores
    op[256] = packmin(b1, i1);
}

// ---------------------------------------------------------------------------
// Kernel 1b (finalize+fallback, merged): per thread (= per sorted vertex),
// u64-min the 8 chunk partials -> lexicographic global-slab winner. If its
// computed d <= 6.2 it is provably the GLOBAL argmin (unscanned residues
// have computed d' >= 6.25-5e-3 > 6.2 by slab geometry — r11/r12 absmax-0
// validated) -> scatter 1.0f into the hit mask. Unresolved lanes (~20%) are
// processed wave-cooperatively via ballot/ffs: for each, the whole wave
// rescans the W2-slab (W2 = sqrt(min(d1,4e4)+1)+1/16, the r7/r12-validated
// bound: any residue that could beat or tie has |dx| < W2, and the pass-1
// winner is inside so the range is non-empty), lanes striding coalesced,
// packed-u64 shuffle reduce -> exact np.argmin. 512 blocks x 256 threads.
// ---------------------------------------------------------------------------
__global__ __launch_bounds__(256) void k_finfb(const float4* __restrict__ vf4g,
                                               const float4* __restrict__ sf4g,
                                               const unsigned int* __restrict__ sidxg,
                                               const unsigned int* __restrict__ cellsg,
                                               const unsigned long long* __restrict__ part,
                                               float* __restrict__ msk) {
    const int p = blockIdx.x * 256 + threadIdx.x;       // 0..B*V-1 (sorted order)
    const int b = p >> 13;
    const int lane = threadIdx.x & 63;

    unsigned long long pk = part[p];
#pragma unroll
    for (int s = 1; s < S_CHK; ++s) {
        const unsigned long long q = part[(size_t)s * NVTOT + p];
        pk = q < pk ? q : pk;                           // u64 < == lex (d, idx) <
    }
    const unsigned int key  = (unsigned int)(pk >> 32);
    const unsigned int kthr = __float_as_uint(RES_D) ^ 0x80000000u;  // flip(6.2)
    const bool resolved = (key <= kthr);
    if (resolved)
        msk[b * N_RES + (unsigned int)(pk & 0xFFFFFFFFu)] = 1.0f;

    // unflip the winner distance (handles the tiny-negative-d case too)
    const float d1 = __uint_as_float(key >= 0x80000000u ? (key ^ 0x80000000u) : ~key);

    unsigned long long um = __ballot(!resolved);
    const int pbase = p & ~63;                          // wave's first vertex
    while (um) {
        const int l = __ffsll((unsigned long long)um) - 1;
        um &= um - 1;
        const int pv = pbase + l;
        const int bb = pv >> 13;
        const float d1v = __shfl(d1, l);
        const float4 v = vf4g[pv];                      // broadcast load
        const float W2 = sqrtf(fminf(d1v, 40000.0f) + 1.0f) + 0.0625f;
        const int j0 = (int)cellsg[bb * CPAD + bucketof(v.x - W2)];
        const int j1 = (int)cellsg[bb * CPAD + bucketof(v.x + W2) + 1];

        float best = 3.402823466e+38f;
        int bidx = 0;
        const float4* sp = sf4g + (size_t)bb * N_RES;
        const unsigned int* ip = sidxg + (size_t)bb * N_RES;
        for (int j = j0 + lane; j < j1; j += 64)        // coalesced lane stride
            eval_one(sp[j], (int)ip[j], v.x, v.y, v.z, v.w, best, bidx);

        unsigned long long w = packmin(best, bidx);
#pragma unroll
        for (int o = 1; o < 64; o <<= 1) {
            const unsigned long long q = __shfl_xor(w, o);
            w = q < w ? q : w;
        }
        if (lane == 0)
            msk[bb * N_RES + (unsigned int)(w & 0xFFFFFFFFu)] = 1.0f;
    }
}

// ---------------------------------------------------------------------------
// Kernel 2: masked-sum a 128-residue slice of feats with float4 loads.
// ---------------------------------------------------------------------------
__global__ __launch_bounds__(256) void k_pool_m(const float* __restrict__ msk,
                                                const float* __restrict__ feats,
                                                float* __restrict__ partial) {
    __shared__ float sm[N_RES / SEGS];
    __shared__ float4 red[8][32];
    const int b   = blockIdx.x >> 4;
    const int seg = blockIdx.x & (SEGS - 1);
    const int n0  = seg * (N_RES / SEGS);

    if (threadIdx.x < N_RES / SEGS) sm[threadIdx.x] = msk[b * N_RES + n0 + threadIdx.x];
    __syncthreads();

    const int q = threadIdx.x & 31;
    const int s = threadIdx.x >> 5;
    const float4* fb4 = (const float4*)(feats + ((size_t)b * N_RES + n0) * H_DIM);

    float4 acc = make_float4(0.f, 0.f, 0.f, 0.f);
#pragma unroll
    for (int n = 0; n < N_RES / SEGS / 8; ++n) {
        const int nn = s + n * 8;
        const float m = sm[nn];
        const float4 f = fb4[(size_t)nn * 32 + q];
        acc.x = fmaf(f.x, m, acc.x);
        acc.y = fmaf(f.y, m, acc.y);
        acc.z = fmaf(f.z, m, acc.z);
        acc.w = fmaf(f.w, m, acc.w);
    }
    red[s][q] = acc;
    __syncthreads();

    if (s == 0) {
        float4 t = acc;
#pragma unroll
        for (int i = 1; i < 8; ++i) {
            t.x += red[i][q].x; t.y += red[i][q].y;
            t.z += red[i][q].z; t.w += red[i][q].w;
        }
        ((float4*)partial)[((size_t)b * SEGS + seg) * 32 + q] = t;
    }
}

// ---------------------------------------------------------------------------
// Fallback path (small workspace): brute-force atomicMin kernels (r0).
// ---------------------------------------------------------------------------
#define NSPLIT 16
#define NL     (N_RES / NSPLIT)
#define FVPT   8
#define FVBLK  (256 * FVPT)
#define FVBLKS (V_PTS / FVBLK)
__global__ __launch_bounds__(256, 4) void k_argmin_at(const float* __restrict__ verts,
                                                      const float* __restrict__ coords,
                                                      unsigned long long* __restrict__ mi64) {
    __shared__ float4 sc[NL];
    const int b  = blockIdx.x / (FVBLKS * NSPLIT);
    const int r  = blockIdx.x % (FVBLKS * NSPLIT);
    const int vb = r / NSPLIT;
    const int ns = r % NSPLIT;

    const float* cbase = coords + ((size_t)b * N_RES + ns * NL) * 3;
    if (threadIdx.x < NL) {
        const int i = threadIdx.x;
        float x = cbase[i * 3 + 0];
        float y = cbase[i * 3 + 1];
        float z = cbase[i * 3 + 2];
        float csq = __fadd_rn(__fadd_rn(__fmul_rn(x, x), __fmul_rn(y, y)), __fmul_rn(z, z));
        sc[i] = make_float4(x, y, z, csq);
    }
    __syncthreads();

    const int vbase = vb * FVBLK + threadIdx.x;
    const float* vp = verts + (size_t)b * V_PTS * 3;

    float vx[FVPT], vy[FVPT], vz[FVPT], vsq[FVPT], best[FVPT];
    int bi[FVPT];
#pragma unroll
    for (int k = 0; k < FVPT; ++k) {
        const int v = vbase + k * 256;
        vx[k] = vp[v * 3 + 0];
        vy[k] = vp[v * 3 + 1];
        vz[k] = vp[v * 3 + 2];
        vsq[k] = __fadd_rn(__fadd_rn(__fmul_rn(vx[k], vx[k]), __fmul_rn(vy[k], vy[k])),
                           __fmul_rn(vz[k], vz[k]));
        best[k] = 3.402823466e+38f;
        bi[k] = 0;
    }
#pragma unroll 2
    for (int n = 0; n < NL; ++n) {
        const float4 c = sc[n];
#pragma unroll
        for (int k = 0; k < FVPT; ++k) {
            float dot = __fadd_rn(__fadd_rn(__fmul_rn(vx[k], c.x), __fmul_rn(vy[k], c.y)),
                                  __fmul_rn(vz[k], c.z));
            float d = __fadd_rn(fmaf(-2.0f, dot, vsq[k]), c.w);
            bool m = d < best[k];
            best[k] = m ? d : best[k];
            bi[k]   = m ? n : bi[k];
        }
    }
#pragma unroll
    for (int k = 0; k < FVPT; ++k) {
        unsigned int bits = __float_as_uint(best[k]);
        unsigned int key  = bits ^ (unsigned int)(((int)bits >> 31) | 0x80000000);
        unsigned long long packed =
            ((unsigned long long)key << 32) | (unsigned int)(ns * NL + bi[k]);
        atomicMin(&mi64[(size_t)b * V_PTS + vbase + k * 256], packed);
    }
}

__global__ __launch_bounds__(256) void k_pool_at(const unsigned long long* __restrict__ mi64,
                                                 const float* __restrict__ feats,
                                                 float* __restrict__ partial) {
    __shared__ float msk[N_RES];
    __shared__ float4 red[8][32];
    const int b   = blockIdx.x >> 4;
    const int seg = blockIdx.x & (SEGS - 1);

    for (int i = threadIdx.x; i < N_RES; i += 256) msk[i] = 0.0f;
    __syncthreads();
    const unsigned long long* mb = mi64 + (size_t)b * V_PTS;
    for (int v = threadIdx.x; v < V_PTS; v += 256)
        msk[(unsigned int)mb[v]] = 1.0f;
    __syncthreads();

    const int q = threadIdx.x & 31;
    const int s = threadIdx.x >> 5;
    const int n0 = seg * (N_RES / SEGS);
    const float4* fb4 = (const float4*)(feats + ((size_t)b * N_RES + n0) * H_DIM);

    float4 acc = make_float4(0.f, 0.f, 0.f, 0.f);
#pragma unroll
    for (int n = 0; n < N_RES / SEGS / 8; ++n) {
        const int nn = s + n * 8;
        const float m = msk[n0 + nn];
        const float4 f = fb4[(size_t)nn * 32 + q];
        acc.x = fmaf(f.x, m, acc.x);
        acc.y = fmaf(f.y, m, acc.y);
        acc.z = fmaf(f.z, m, acc.z);
        acc.w = fmaf(f.w, m, acc.w);
    }
    red[s][q] = acc;
    __syncthreads();
    if (s == 0) {
        float4 t = acc;
#pragma unroll
        for (int i = 1; i < 8; ++i) {
            t.x += red[i][q].x; t.y += red[i][q].y;
            t.z += red[i][q].z; t.w += red[i][q].w;
        }
        ((float4*)partial)[((size_t)b * SEGS + seg) * 32 + q] = t;
    }
}

// ---------------------------------------------------------------------------
// Kernel 3: per-graph pooled reduce + MLP. 16 blocks x 128 threads.
// (r1 lesson: last-block-done fusion costs more than the launch it saves.)
// ---------------------------------------------------------------------------
__global__ __launch_bounds__(128) void k_mlp(const float* __restrict__ partial,
                                             const float* __restrict__ W1,
                                             const float* __restrict__ b1,
                                             const float* __restrict__ W2,
                                             const float* __restrict__ b2,
                                             float* __restrict__ out) {
    __shared__ float pooled[H_DIM];
    __shared__ float h1[H_DIM];
    const int b = blockIdx.x;
    const int j = threadIdx.x;

    float s = 0.0f;
#pragma unroll
    for (int g = 0; g < SEGS; ++g)
        s += partial[((size_t)b * SEGS + g) * H_DIM + j];
    pooled[j] = s;
    __syncthreads();

    float acc = b1[j];
#pragma unroll 8
    for (int hh = 0; hh < H_DIM; ++hh)
        acc = fmaf(pooled[hh], W1[hh * H_DIM + j], acc);
    h1[j] = fmaxf(acc, 0.0f);
    __syncthreads();

    if (j < C_OUT) {
        float o = b2[j];
#pragma unroll 8
        for (int hh = 0; hh < H_DIM; ++hh)
            o = fmaf(h1[hh], W2[hh * C_OUT + j], o);
        out[(size_t)b * C_OUT + j] = o;
    }
}

extern "C" void kernel_launch(void* const* d_in, const int* in_sizes, int n_in,
                              void* d_out, int out_size, void* d_ws, size_t ws_size,
                              hipStream_t stream) {
    const float* verts  = (const float*)d_in[0];   // [B,V,3]
    const float* coords = (const float*)d_in[1];   // [B,N,3]
    const float* feats  = (const float*)d_in[2];   // [B,N,H]
    const float* W1     = (const float*)d_in[3];   // [H,H]
    const float* b1     = (const float*)d_in[4];   // [H]
    const float* W2     = (const float*)d_in[5];   // [H,C_OUT]
    const float* b2     = (const float*)d_in[6];   // [C_OUT]
    float* out = (float*)d_out;                    // [B,C_OUT]

    // workspace layout (~11 MB)
    const size_t vf4_bytes  = (size_t)B_GR * V_PTS * 16;       // 2 MB
    const size_t sf4_bytes  = (size_t)B_GR * N_RES * 16;       // 512 KB
    const size_t sidx_bytes = (size_t)B_GR * N_RES * 4;        // 128 KB
    const size_t cell_bytes = (size_t)B_GR * CPAD * 4;         // ~33 KB
    const size_t msk_bytes  = (size_t)B_GR * N_RES * 4;        // 128 KB
    const size_t pp_bytes   = (size_t)B_GR * SEGS * H_DIM * 4; // 128 KB
    const size_t part_bytes = (size_t)S_CHK * NVTOT * 8;       // 8 MB
    const size_t need = vf4_bytes + sf4_bytes + sidx_bytes + cell_bytes +
                        msk_bytes + pp_bytes + part_bytes;

    if (ws_size >= need) {
        char* p = (char*)d_ws;
        float4*             vf4g  = (float4*)p;             p += vf4_bytes;
        float4*             sf4g  = (float4*)p;             p += sf4_bytes;
        unsigned int*       sidxg = (unsigned int*)p;       p += sidx_bytes;
        unsigned int*       cells = (unsigned int*)p;       p += cell_bytes;
        float*              msk   = (float*)p;              p += msk_bytes;
        float*              partial = (float*)p;            p += pp_bytes;
        unsigned long long* part  = (unsigned long long*)p;

        // 5 graph nodes, 0 memsets (all intermediates fully rewritten each replay)
        k_prep  <<<B_GR,               256, 0, stream>>>(coords, verts, sf4g, sidxg,
                                                         cells, vf4g, msk);
        k_search<<<B_GR * 16 * S_CHK,  256, 0, stream>>>(vf4g, sf4g, sidxg, cells, part);
        k_finfb <<<B_GR * V_PTS / 256, 256, 0, stream>>>(vf4g, sf4g, sidxg, cells,
                                                         part, msk);
        k_pool_m<<<B_GR * SEGS,        256, 0, stream>>>(msk, feats, partial);
        k_mlp   <<<B_GR,               128, 0, stream>>>(partial, W1, b1, W2, b2, out);
    } else {
        // ---- fallback: brute-force atomicMin path ----
        unsigned long long* mi64 = (unsigned long long*)d_ws;              // 1 MB
        float* partial = (float*)((char*)d_ws + (size_t)B_GR * V_PTS * 8); // 128 KB

        hipMemsetAsync(mi64, 0xFF, (size_t)B_GR * V_PTS * 8, stream);
        k_argmin_at<<<B_GR * FVBLKS * NSPLIT, 256, 0, stream>>>(verts, coords, mi64);
        k_pool_at  <<<B_GR * SEGS,            256, 0, stream>>>(mi64, feats, partial);
        k_mlp      <<<B_GR,                   128, 0, stream>>>(partial, W1, b1, W2, b2, out);
    }
}